// Round 5
// baseline (90273.462 us; speedup 1.0000x reference)
//
#include <hip/hip_runtime.h>

#define NWG 256
#define WGS 512

typedef __attribute__((ext_vector_type(4))) float facc4;
typedef __attribute__((ext_vector_type(8))) short bfrag8;
#define MFMA_BF16 __builtin_amdgcn_mfma_f32_16x16x32_bf16

constexpr int B_ = 128, T_ = 512, I_ = 128, H_ = 1024;
constexpr int G_ = 4 * H_;

// ---------------- workspace layout (bytes) ----------------
constexpr size_t OFF_BAR  = 0;                                   // tree barrier (1 KB)
constexpr size_t OFF_H1F  = 1024;                                // 2 x B*H fp32
constexpr size_t OFF_H2F  = OFF_H1F + 2ull * B_ * H_ * 4;
constexpr size_t OFF_C1   = OFF_H2F + 2ull * B_ * H_ * 4;
constexpr size_t OFF_C2   = OFF_C1 + (size_t)B_ * H_ * 4;
constexpr size_t OFF_X1F  = OFF_C2 + (size_t)B_ * H_ * 4;        // B*I fp32
constexpr size_t OFF_X2F  = OFF_X1F + (size_t)B_ * I_ * 4;       // B*H fp32
constexpr size_t OFF_H1S  = OFF_X2F + (size_t)B_ * H_ * 4;       // 2 x B*H bf16
constexpr size_t OFF_H2S  = OFF_H1S + 2ull * B_ * H_ * 2;
constexpr size_t OFF_X1S  = OFF_H2S + 2ull * B_ * H_ * 2;        // B*I bf16
constexpr size_t OFF_X2S  = OFF_X1S + (size_t)B_ * I_ * 2;       // B*H bf16
constexpr size_t OFF_BS1  = OFF_X2S + (size_t)B_ * H_ * 2;       // 4096 fp32
constexpr size_t OFF_BS2  = OFF_BS1 + (size_t)G_ * 4;
constexpr size_t ZERO_BYTES = OFF_BS2 + (size_t)G_ * 4;
// not zeroed (write-before-read / re-converted each launch):
constexpr size_t OFF_G1P  = ZERO_BYTES;                          // [4][128][1024] fp32 gate planes
constexpr size_t OFF_G2P  = OFF_G1P + 4ull * B_ * H_ * 4;
constexpr size_t OFF_WQ1B = OFF_G2P + 4ull * B_ * H_ * 4;        // 3*128*1024 bf16
constexpr size_t OFF_WR1B = OFF_WQ1B + 3ull * I_ * H_ * 2;       // 2*1024*128 bf16
constexpr size_t OFF_WR21B = OFF_WR1B + 2ull * H_ * I_ * 2;      // 1024*1024 bf16 (wr2[1])

struct GBar { unsigned leaf[32]; unsigned root; unsigned gen; };

__device__ __forceinline__ float sigf(float x) { return 1.0f / (1.0f + __expf(-x)); }

__device__ __forceinline__ unsigned short f2bf(float f) {
  union { float f; unsigned u; } v; v.f = f;
  unsigned r = v.u + 0x7FFFu + ((v.u >> 16) & 1u);  // RNE
  return (unsigned short)(r >> 16);
}

// ---- fence-ful device barrier (R1-validated). L2 holds only per-stage
// activations now, so the release wbl2 / acquire inv are cheap AND correct.
__device__ __forceinline__ void gbar(GBar* b) {
  __syncthreads();
  if (threadIdx.x == 0) {
    __builtin_amdgcn_fence(__ATOMIC_RELEASE, "agent");
    unsigned g = __hip_atomic_load(&b->gen, __ATOMIC_RELAXED, __HIP_MEMORY_SCOPE_AGENT);
    int leaf = blockIdx.x >> 3;
    unsigned a = __hip_atomic_fetch_add(&b->leaf[leaf], 1u, __ATOMIC_RELAXED,
                                        __HIP_MEMORY_SCOPE_AGENT);
    if (a == 7u) {
      unsigned r = __hip_atomic_fetch_add(&b->root, 1u, __ATOMIC_RELAXED,
                                          __HIP_MEMORY_SCOPE_AGENT);
      if (r == 31u) {
        for (int i = 0; i < 32; i++)
          __hip_atomic_store(&b->leaf[i], 0u, __ATOMIC_RELAXED, __HIP_MEMORY_SCOPE_AGENT);
        __hip_atomic_store(&b->root, 0u, __ATOMIC_RELAXED, __HIP_MEMORY_SCOPE_AGENT);
        __hip_atomic_store(&b->gen, g + 1u, __ATOMIC_RELEASE, __HIP_MEMORY_SCOPE_AGENT);
      }
    }
    while (__hip_atomic_load(&b->gen, __ATOMIC_RELAXED, __HIP_MEMORY_SCOPE_AGENT) == g)
      __builtin_amdgcn_s_sleep(1);
    __builtin_amdgcn_fence(__ATOMIC_ACQUIRE, "agent");
  }
  __syncthreads();
}

// ---- mogrify unit: WG owns 16 output cols (nbase..nbase+15), all 128 batch rows.
// 8 waves = 8 m-tiles. W from pinned LDS (stride K+8) or global bf16 (stride K).
// Epilogue per-wave: dst = 2*sigmoid(acc+bias)*src. All plain (cached) accesses.
template <int K, bool WLDS>
__device__ __forceinline__ void mog_u(
    const unsigned short* A,              // [128][K] bf16
    const unsigned short* Wrows,          // 16 rows (LDS tile or global rows base)
    const float* bias, int nbase,         // bias[nbase+l15]
    const float* srcF, int srcStride, int srcOff,
    float* dstF, unsigned short* dstS, int N) {
  const int tid = threadIdx.x, lane = tid & 63, mt = tid >> 6;
  const int l15 = lane & 15, lq = lane >> 4;
  constexpr int WSTR = WLDS ? K + 8 : K;
  const unsigned short* ap = A + (size_t)(mt * 16 + l15) * K + lq * 8;
  const unsigned short* wp = Wrows + (size_t)l15 * WSTR + lq * 8;
  facc4 acc = {0.f, 0.f, 0.f, 0.f};
#pragma unroll 8
  for (int k = 0; k < K; k += 32)
    acc = MFMA_BF16(*(const bfrag8*)(ap + k), *(const bfrag8*)(wp + k), acc, 0, 0, 0);
  const int n = nbase + l15;
  const float bn = bias[n];
#pragma unroll
  for (int j = 0; j < 4; j++) {
    const int m = mt * 16 + lq * 4 + j;
    float v = 2.0f * sigf(acc[j] + bn) * srcF[(size_t)m * srcStride + srcOff + n];
    dstF[(size_t)m * N + n] = v;
    float vo = __shfl_xor(v, 1);
    if (!(l15 & 1)) {
      unsigned pk = (unsigned)f2bf(v) | ((unsigned)f2bf(vo) << 16);
      *(unsigned*)(dstS + (size_t)m * N + n) = pk;
    }
  }
}

__global__ __launch_bounds__(WGS, 1) void moglstm_kernel(
    const float* __restrict__ in_seq,
    const float* __restrict__ c1Q, const float* __restrict__ c1Qb,
    const float* __restrict__ c1R, const float* __restrict__ c1Rb,
    const float* __restrict__ c1Wih, const float* __restrict__ c1Whh,
    const float* __restrict__ c1bih, const float* __restrict__ c1bhh,
    const float* __restrict__ c2Q, const float* __restrict__ c2Qb,
    const float* __restrict__ c2R, const float* __restrict__ c2Rb,
    const float* __restrict__ c2Wih, const float* __restrict__ c2Whh,
    const float* __restrict__ c2bih, const float* __restrict__ c2bhh,
    const float* __restrict__ linW, const float* __restrict__ linb,
    char* ws, float* __restrict__ out) {
  // pinned weights (strides padded +8 els: 16B-aligned rows, ~2-way banks = free)
  __shared__ unsigned short pin_c2[16 * 2056];  // cell2: 16 rows x [x(1024)|h(1024)]
  __shared__ unsigned short pin_c1[16 * 1160];  // cell1: 16 rows x [x(128)|h(1024)]
  __shared__ unsigned short pin_t[16 * 1032];   // wq2[cl] (cl<3) or wr2[0] (cl==3)
  __shared__ float fin[WGS];

  GBar* bar = (GBar*)(ws + OFF_BAR);
  float* h1f0 = (float*)(ws + OFF_H1F);
  float* h1f1 = h1f0 + (size_t)B_ * H_;
  float* h2f0 = (float*)(ws + OFF_H2F);
  float* h2f1 = h2f0 + (size_t)B_ * H_;
  float* c1f = (float*)(ws + OFF_C1);
  float* c2f = (float*)(ws + OFF_C2);
  float* x1f = (float*)(ws + OFF_X1F);
  float* x2f = (float*)(ws + OFF_X2F);
  unsigned short* h1s0 = (unsigned short*)(ws + OFF_H1S);
  unsigned short* h1s1 = h1s0 + (size_t)B_ * H_;
  unsigned short* h2s0 = (unsigned short*)(ws + OFF_H2S);
  unsigned short* h2s1 = h2s0 + (size_t)B_ * H_;
  unsigned short* x1s = (unsigned short*)(ws + OFF_X1S);
  unsigned short* x2s = (unsigned short*)(ws + OFF_X2S);
  float* bs1 = (float*)(ws + OFF_BS1);
  float* bs2 = (float*)(ws + OFF_BS2);
  float* g1p = (float*)(ws + OFF_G1P);
  float* g2p = (float*)(ws + OFF_G2P);
  unsigned short* wq1bf = (unsigned short*)(ws + OFF_WQ1B);
  unsigned short* wr1bf = (unsigned short*)(ws + OFF_WR1B);
  unsigned short* wr21bf = (unsigned short*)(ws + OFF_WR21B);

  const int wg = blockIdx.x;
  const int tid = threadIdx.x;
  const int cl = wg & 3;        // gate / mog-tile class
  const int nt = wg >> 2;       // 0..63 (16-col slice owner)

  // ---- init: pin this WG's weight slices into LDS (fp32 -> bf16)
  for (int i = tid; i < 16 * 2048; i += WGS) {
    int r = i >> 11, k = i & 2047;
    int row = cl * H_ + nt * 16 + r;
    float v = (k < 1024) ? c2Wih[(size_t)row * H_ + k] : c2Whh[(size_t)row * H_ + (k - 1024)];
    pin_c2[r * 2056 + k] = f2bf(v);
  }
  for (int i = tid; i < 16 * 1152; i += WGS) {
    int r = i / 1152, k = i - r * 1152;
    int row = cl * H_ + nt * 16 + r;
    float v = (k < 128) ? c1Wih[(size_t)row * I_ + k] : c1Whh[(size_t)row * H_ + (k - 128)];
    pin_c1[r * 1160 + k] = f2bf(v);
  }
  for (int i = tid; i < 16 * 1024; i += WGS) {
    int r = i >> 10, k = i & 1023;
    const float* src = (cl < 3) ? (c2Q + (size_t)cl * H_ * H_) : c2R;  // wr2[0]
    pin_t[r * 1032 + k] = f2bf(src[(size_t)(nt * 16 + r) * H_ + k]);
  }
  // ---- init: L2-streamed small weights (bf16) + bias sums (plain stores)
  {
    size_t gt = (size_t)wg * WGS + tid;
    const size_t gs = (size_t)NWG * WGS;
    for (size_t i = gt; i < 3ull * I_ * H_; i += gs) wq1bf[i] = f2bf(c1Q[i]);
    for (size_t i = gt; i < 2ull * H_ * I_; i += gs) wr1bf[i] = f2bf(c1R[i]);
    for (size_t i = gt; i < 1ull * H_ * H_; i += gs) wr21bf[i] = f2bf(c2R[(size_t)H_ * H_ + i]);
    for (size_t i = gt; i < (size_t)G_; i += gs) bs1[i] = c1bih[i] + c1bhh[i];
    for (size_t i = gt; i < (size_t)G_; i += gs) bs2[i] = c2bih[i] + c2bhh[i];
  }
  gbar(bar);

  // phase p: layer-1 step t=p and layer-2 step t=p-1
  for (int p = 0; p <= T_; ++p) {
    const int q = p & 1;
    const bool doL1 = (p < T_);
    const bool doL2 = (p > 0);
    float* h1q = q ? h1f1 : h1f0;          // L1 state (read + R-round in-place)
    float* h1o = q ? h1f0 : h1f1;          // cell1 epilogue writes
    unsigned short* h1sq = q ? h1s1 : h1s0;
    unsigned short* h1so = q ? h1s0 : h1s1;
    float* h2q2 = q ? h2f0 : h2f1;         // L2 state parity (p-1)&1
    float* h2o = q ? h2f1 : h2f0;          // cell2 epilogue writes parity q
    unsigned short* h2sq2 = q ? h2s0 : h2s1;
    unsigned short* h2so = q ? h2s1 : h2s0;

    // s0: mog2-Q1 (cl==0, pinned) || mog1-Q1 (cl==3, nt<8, L2 weights)
    if (doL2 && cl == 0)
      mog_u<1024, true>(h2sq2, pin_t, c2Qb, nt * 16, h1q, H_, 0, x2f, x2s, H_);
    if (doL1 && cl == 3 && nt < 8)
      mog_u<1024, false>(h1sq, wq1bf + (size_t)nt * 16 * H_, c1Qb, nt * 16,
                         in_seq, T_ * I_, p * I_, x1f, x1s, I_);
    gbar(bar);
    // s1: mog2-R1 (cl==3, pinned wr2[0]) || mog1-R1 (cl==1, L2)
    if (doL2 && cl == 3)
      mog_u<1024, true>(x2s, pin_t, c2Rb, nt * 16, h2q2, H_, 0, h2q2, h2sq2, H_);
    if (doL1 && cl == 1)
      mog_u<128, false>(x1s, wr1bf + (size_t)nt * 16 * I_, c1Rb, nt * 16,
                        h1q, H_, 0, h1q, h1sq, H_);
    gbar(bar);
    // s2: mog2-Q2 (cl==1, pinned) || mog1-Q2 (cl==3, 8<=nt<16)
    if (doL2 && cl == 1)
      mog_u<1024, true>(h2sq2, pin_t, c2Qb + H_, nt * 16, x2f, H_, 0, x2f, x2s, H_);
    if (doL1 && cl == 3 && nt >= 8 && nt < 16)
      mog_u<1024, false>(h1sq, wq1bf + (1ull * I_ * H_) + (size_t)(nt - 8) * 16 * H_,
                         c1Qb + I_, (nt - 8) * 16, x1f, I_, 0, x1f, x1s, I_);
    gbar(bar);
    // s3: mog2-R2 (cl==2, L2 wr2[1]) || mog1-R2 (cl==0, L2)
    if (doL2 && cl == 2)
      mog_u<1024, false>(x2s, wr21bf + (size_t)nt * 16 * H_, c2Rb + H_, nt * 16,
                         h2q2, H_, 0, h2q2, h2sq2, H_);
    if (doL1 && cl == 0)
      mog_u<128, false>(x1s, wr1bf + (1ull * H_ * I_) + (size_t)nt * 16 * I_,
                        c1Rb + H_, nt * 16, h1q, H_, 0, h1q, h1sq, H_);
    gbar(bar);
    // s4: mog2-Q3 (cl==2, pinned) || mog1-Q3 (cl==3, 16<=nt<24)
    if (doL2 && cl == 2)
      mog_u<1024, true>(h2sq2, pin_t, c2Qb + 2 * H_, nt * 16, x2f, H_, 0, x2f, x2s, H_);
    if (doL1 && cl == 3 && nt >= 16 && nt < 24)
      mog_u<1024, false>(h1sq, wq1bf + (2ull * I_ * H_) + (size_t)(nt - 16) * 16 * H_,
                         c1Qb + 2 * I_, (nt - 16) * 16, x1f, I_, 0, x1f, x1s, I_);
    gbar(bar);
    // s5: cell gate partials (all WGs: gate=cl, cols nt*16..), fp32 planes
    {
      const int lane = tid & 63, mt = tid >> 6;
      const int l15 = lane & 15, lq = lane >> 4;
      const int ncol = nt * 16 + l15;
      if (doL2) {
        const unsigned short* ax = x2s + (size_t)(mt * 16 + l15) * H_ + lq * 8;
        const unsigned short* ah = h2sq2 + (size_t)(mt * 16 + l15) * H_ + lq * 8;
        const unsigned short* wp = pin_c2 + l15 * 2056 + lq * 8;
        facc4 acc = {0.f, 0.f, 0.f, 0.f};
#pragma unroll 8
        for (int k = 0; k < 1024; k += 32)
          acc = MFMA_BF16(*(const bfrag8*)(ax + k), *(const bfrag8*)(wp + k), acc, 0, 0, 0);
#pragma unroll 8
        for (int k = 0; k < 1024; k += 32)
          acc = MFMA_BF16(*(const bfrag8*)(ah + k), *(const bfrag8*)(wp + 1024 + k), acc, 0, 0, 0);
#pragma unroll
        for (int j = 0; j < 4; j++)
          g2p[((size_t)cl * B_ + mt * 16 + lq * 4 + j) * H_ + ncol] = acc[j];
      }
      if (doL1) {
        const unsigned short* ax = x1s + (size_t)(mt * 16 + l15) * I_ + lq * 8;
        const unsigned short* ah = h1sq + (size_t)(mt * 16 + l15) * H_ + lq * 8;
        const unsigned short* wp = pin_c1 + l15 * 1160 + lq * 8;
        facc4 acc = {0.f, 0.f, 0.f, 0.f};
#pragma unroll
        for (int k = 0; k < 128; k += 32)
          acc = MFMA_BF16(*(const bfrag8*)(ax + k), *(const bfrag8*)(wp + k), acc, 0, 0, 0);
#pragma unroll 8
        for (int k = 0; k < 1024; k += 32)
          acc = MFMA_BF16(*(const bfrag8*)(ah + k), *(const bfrag8*)(wp + 128 + k), acc, 0, 0, 0);
#pragma unroll
        for (int j = 0; j < 4; j++)
          g1p[((size_t)cl * B_ + mt * 16 + lq * 4 + j) * H_ + ncol] = acc[j];
      }
    }
    gbar(bar);
    // s6: cell epilogues — 1 (cell, m, n-pair) per thread
    {
      const int e = wg * WGS + tid;          // 0..131071
      const int cell = e >> 16;              // 0 -> cell1, 1 -> cell2
      const int pr = e & 65535;
      const int m = pr >> 9;
      const int n = (pr & 511) * 2;
      if (cell ? doL2 : doL1) {
        const float* gp = cell ? g2p : g1p;
        const float* bs = cell ? bs2 : bs1;
        float* cst = cell ? c2f : c1f;
        float* hF = cell ? h2o : h1o;
        unsigned short* hS = cell ? h2so : h1so;
        unsigned pk = 0;
#pragma unroll
        for (int d = 0; d < 2; d++) {
          const int nn = n + d;
          float gi = gp[((size_t)0 * B_ + m) * H_ + nn] + bs[nn];
          float gf = gp[((size_t)1 * B_ + m) * H_ + nn] + bs[H_ + nn];
          float gg = gp[((size_t)2 * B_ + m) * H_ + nn] + bs[2 * H_ + nn];
          float go = gp[((size_t)3 * B_ + m) * H_ + nn] + bs[3 * H_ + nn];
          const size_t idx = (size_t)m * H_ + nn;
          float cn = sigf(gf) * cst[idx] + sigf(gi) * tanhf(gg);
          float hn = sigf(go) * tanhf(cn);
          cst[idx] = cn;
          hF[idx] = hn;
          pk |= ((unsigned)f2bf(hn)) << (16 * d);
        }
        *(unsigned*)(hS + (size_t)m * H_ + n) = pk;
      }
    }
    gbar(bar);
  }

  // ---- final linear: out[b] = dot(h2f0[b,:], linW) + linb
  if (wg == 0) {
    const int b = tid >> 2, qq = tid & 3;
    const float* row = h2f0 + (size_t)b * H_ + qq * 256;
    const float* w = linW + qq * 256;
    float s = 0.f;
    for (int k = 0; k < 256; k++) s += row[k] * w[k];
    fin[tid] = s;
    __syncthreads();
    if (tid < B_)
      out[tid] = fin[tid * 4] + fin[tid * 4 + 1] + fin[tid * 4 + 2] + fin[tid * 4 + 3] + linb[0];
  }
}

extern "C" void kernel_launch(void* const* d_in, const int* in_sizes, int n_in,
                              void* d_out, int out_size, void* d_ws, size_t ws_size,
                              hipStream_t stream) {
  const float* in_seq = (const float*)d_in[0];
  const float* c1Q = (const float*)d_in[1];
  const float* c1Qb = (const float*)d_in[2];
  const float* c1R = (const float*)d_in[3];
  const float* c1Rb = (const float*)d_in[4];
  const float* c1Wih = (const float*)d_in[5];
  const float* c1Whh = (const float*)d_in[6];
  const float* c1bih = (const float*)d_in[7];
  const float* c1bhh = (const float*)d_in[8];
  const float* c2Q = (const float*)d_in[9];
  const float* c2Qb = (const float*)d_in[10];
  const float* c2R = (const float*)d_in[11];
  const float* c2Rb = (const float*)d_in[12];
  const float* c2Wih = (const float*)d_in[13];
  const float* c2Whh = (const float*)d_in[14];
  const float* c2bih = (const float*)d_in[15];
  const float* c2bhh = (const float*)d_in[16];
  const float* linW = (const float*)d_in[17];
  const float* linb = (const float*)d_in[18];

  hipMemsetAsync(d_ws, 0, ZERO_BYTES, stream);
  moglstm_kernel<<<dim3(NWG), dim3(WGS), 0, stream>>>(
      in_seq, c1Q, c1Qb, c1R, c1Rb, c1Wih, c1Whh, c1bih, c1bhh,
      c2Q, c2Qb, c2R, c2Rb, c2Wih, c2Whh, c2bih, c2bhh,
      linW, linb, (char*)d_ws, (float*)d_out);
}

// Round 6
// 74772.870 us; speedup vs baseline: 1.2073x; 1.2073x over previous
//
#include <hip/hip_runtime.h>

#define NWG 256
#define WGS 512

typedef __attribute__((ext_vector_type(4))) float facc4;
typedef __attribute__((ext_vector_type(8))) short bfrag8;
#define MFMA_BF16 __builtin_amdgcn_mfma_f32_16x16x32_bf16

constexpr int B_ = 128, T_ = 512, I_ = 128, H_ = 1024;
constexpr int G_ = 4 * H_;

// ---------------- workspace layout (bytes) ----------------
constexpr size_t OFF_BAR  = 0;                                   // tree barrier
constexpr size_t OFF_H1F  = 1024;                                // 2 x B*H fp32
constexpr size_t OFF_H2F  = OFF_H1F + 2ull * B_ * H_ * 4;
constexpr size_t OFF_C1   = OFF_H2F + 2ull * B_ * H_ * 4;
constexpr size_t OFF_C2   = OFF_C1 + (size_t)B_ * H_ * 4;
constexpr size_t OFF_X1F  = OFF_C2 + (size_t)B_ * H_ * 4;        // B*I fp32
constexpr size_t OFF_X2F  = OFF_X1F + (size_t)B_ * I_ * 4;       // B*H fp32
constexpr size_t OFF_H1S  = OFF_X2F + (size_t)B_ * H_ * 4;       // 2 x B*H bf16
constexpr size_t OFF_H2S  = OFF_H1S + 2ull * B_ * H_ * 2;
constexpr size_t OFF_X1S  = OFF_H2S + 2ull * B_ * H_ * 2;        // B*I bf16
constexpr size_t OFF_X2S  = OFF_X1S + (size_t)B_ * I_ * 2;       // B*H bf16
constexpr size_t OFF_BS1  = OFF_X2S + (size_t)B_ * H_ * 2;       // 4096 fp32
constexpr size_t OFF_BS2  = OFF_BS1 + (size_t)G_ * 4;
constexpr size_t ZERO_BYTES = OFF_BS2 + (size_t)G_ * 4;
// not zeroed (write-before-read / re-converted each launch):
constexpr size_t OFF_G1P  = ZERO_BYTES;                          // [4 Kq][128][4096] fp32
constexpr size_t OFF_G2P  = OFF_G1P + 4ull * B_ * G_ * 4;
constexpr size_t OFF_WQ1B = OFF_G2P + 4ull * B_ * G_ * 4;        // 3*128*1024 bf16
constexpr size_t OFF_WR1B = OFF_WQ1B + 3ull * I_ * H_ * 2;       // 2*1024*128 bf16
constexpr size_t OFF_WQ2B = OFF_WR1B + 2ull * H_ * I_ * 2;       // 3*1024*1024 bf16
constexpr size_t OFF_WR2B = OFF_WQ2B + 3ull * H_ * H_ * 2;       // 2*1024*1024 bf16

struct GBar { unsigned leaf[32]; unsigned root; unsigned gen; };

__device__ __forceinline__ float sigf(float x) { return 1.0f / (1.0f + __expf(-x)); }

__device__ __forceinline__ unsigned short f2bf(float f) {
  union { float f; unsigned u; } v; v.f = f;
  unsigned r = v.u + 0x7FFFu + ((v.u >> 16) & 1u);  // RNE
  return (unsigned short)(r >> 16);
}

// ---------- device-coherent (sc0 sc1) data plane for all cross-WG data ----------
__device__ __forceinline__ float cloadf(const float* p) {
  return __hip_atomic_load(p, __ATOMIC_RELAXED, __HIP_MEMORY_SCOPE_AGENT);
}
__device__ __forceinline__ void cstoref(float* p, float v) {
  __hip_atomic_store(p, v, __ATOMIC_RELAXED, __HIP_MEMORY_SCOPE_AGENT);
}
__device__ __forceinline__ void cstoreu(unsigned* p, unsigned v) {
  __hip_atomic_store(p, v, __ATOMIC_RELAXED, __HIP_MEMORY_SCOPE_AGENT);
}
// pack bf16 pair: even lane stores (v, neighbor v) as one u32
__device__ __forceinline__ void cstore_sh(unsigned short* base, size_t idx, float v, int pl) {
  float vo = __shfl_xor(v, 1);
  if (!(pl & 1)) {
    unsigned pk = (unsigned)f2bf(v) | ((unsigned)f2bf(vo) << 16);
    cstoreu((unsigned*)(base + idx), pk);
  }
}

// bulk coherent stage: rows x (C4*4) bf16 -> LDS (whole WG). src pre-offset.
template <int C4>
__device__ __forceinline__ void stage_c(unsigned short* lds, int ldsStride, int ldsColOff,
                                        const unsigned short* src, int srcStride, int rows) {
  const int total = rows * C4;
  for (int i = threadIdx.x; i < total; i += WGS) {
    int r = i / C4, q = (i % C4) * 4;
    unsigned long long v = __hip_atomic_load(
        (const unsigned long long*)(src + (size_t)r * srcStride + q),
        __ATOMIC_RELAXED, __HIP_MEMORY_SCOPE_AGENT);
    *(unsigned long long*)(lds + r * ldsStride + ldsColOff + q) = v;
  }
}

// ---- relaxed barrier: NO per-WG cache maintenance. __syncthreads + explicit
// vmcnt drain put this WG's coherent stores at the L3 coherence point; arrival
// add is relaxed. Only the root's gen-publish is RELEASE (1 wbl2/stage total).
__device__ __forceinline__ void gbar(GBar* b) {
  __syncthreads();
  if (threadIdx.x == 0) {
    asm volatile("s_waitcnt vmcnt(0)" ::: "memory");
    unsigned g = __hip_atomic_load(&b->gen, __ATOMIC_RELAXED, __HIP_MEMORY_SCOPE_AGENT);
    int leaf = blockIdx.x >> 3;
    unsigned a = __hip_atomic_fetch_add(&b->leaf[leaf], 1u, __ATOMIC_RELAXED,
                                        __HIP_MEMORY_SCOPE_AGENT);
    if (a == 7u) {
      unsigned r = __hip_atomic_fetch_add(&b->root, 1u, __ATOMIC_RELAXED,
                                          __HIP_MEMORY_SCOPE_AGENT);
      if (r == 31u) {
        for (int i = 0; i < 32; i++)
          __hip_atomic_store(&b->leaf[i], 0u, __ATOMIC_RELAXED, __HIP_MEMORY_SCOPE_AGENT);
        __hip_atomic_store(&b->root, 0u, __ATOMIC_RELAXED, __HIP_MEMORY_SCOPE_AGENT);
        __hip_atomic_store(&b->gen, g + 1u, __ATOMIC_RELEASE, __HIP_MEMORY_SCOPE_AGENT);
      }
    }
    while (__hip_atomic_load(&b->gen, __ATOMIC_RELAXED, __HIP_MEMORY_SCOPE_AGENT) == g)
      __builtin_amdgcn_s_sleep(1);
    asm volatile("" ::: "memory");
  }
  __syncthreads();
}

// ---- full-fence barrier: ONCE after init (weights/biases are plain stores)
__device__ __forceinline__ void gbar_init(GBar* b) {
  __syncthreads();
  if (threadIdx.x == 0) {
    __builtin_amdgcn_fence(__ATOMIC_RELEASE, "agent");
    unsigned g = __hip_atomic_load(&b->gen, __ATOMIC_RELAXED, __HIP_MEMORY_SCOPE_AGENT);
    int leaf = blockIdx.x >> 3;
    unsigned a = __hip_atomic_fetch_add(&b->leaf[leaf], 1u, __ATOMIC_RELAXED,
                                        __HIP_MEMORY_SCOPE_AGENT);
    if (a == 7u) {
      unsigned r = __hip_atomic_fetch_add(&b->root, 1u, __ATOMIC_RELAXED,
                                          __HIP_MEMORY_SCOPE_AGENT);
      if (r == 31u) {
        for (int i = 0; i < 32; i++)
          __hip_atomic_store(&b->leaf[i], 0u, __ATOMIC_RELAXED, __HIP_MEMORY_SCOPE_AGENT);
        __hip_atomic_store(&b->root, 0u, __ATOMIC_RELAXED, __HIP_MEMORY_SCOPE_AGENT);
        __hip_atomic_store(&b->gen, g + 1u, __ATOMIC_RELEASE, __HIP_MEMORY_SCOPE_AGENT);
      }
    }
    while (__hip_atomic_load(&b->gen, __ATOMIC_RELAXED, __HIP_MEMORY_SCOPE_AGENT) == g)
      __builtin_amdgcn_s_sleep(1);
    __builtin_amdgcn_fence(__ATOMIC_ACQUIRE, "agent");
  }
  __syncthreads();
}

// ---- mogrify unit: 2 16x16 tiles (same mt, nt=ntBase..+1), 8 waves = 2 slots x 4 Kq.
// A coherent-staged to LDS; W plain (L2-resident via XCD-sliced nt ownership).
template <int K, bool SRCCOH>
__device__ __forceinline__ void mog_unit(
    const unsigned short* A,              // [B][K] bf16 coherent
    const unsigned short* W,              // [N][K] bf16 plain
    const float* __restrict__ bias,
    const float* srcF, int srcStride, int srcOff,
    float* dstF, unsigned short* dstS, int N,
    int mt, int ntBase, unsigned short* As, float (*red)[4][64]) {
  constexpr int LSTR = K + 8;
  const int tid = threadIdx.x, lane = tid & 63, wv = tid >> 6;
  const int slot = wv >> 2, role = wv & 3;
  const int nt = ntBase + slot;
  const int l15 = lane & 15, lq = lane >> 4;

  stage_c<K / 4>(As, LSTR, 0, A + (size_t)(mt * 16) * K, K, 16);
  __syncthreads();

  const unsigned short* ap = As + l15 * LSTR + lq * 8;
  const unsigned short* wp = W + (size_t)(nt * 16 + l15) * K + lq * 8;
  constexpr int kq = K / 4;
  facc4 acc = {0.f, 0.f, 0.f, 0.f};
#pragma unroll
  for (int k = 0; k < kq; k += 32)
    acc = MFMA_BF16(*(const bfrag8*)(ap + role * kq + k),
                    *(const bfrag8*)(wp + role * kq + k), acc, 0, 0, 0);
  red[wv][0][lane] = acc[0]; red[wv][1][lane] = acc[1];
  red[wv][2][lane] = acc[2]; red[wv][3][lane] = acc[3];
  __syncthreads();
  if (role == 0) {
    const int n = nt * 16 + l15;
    const float bn = bias[n];
#pragma unroll
    for (int j = 0; j < 4; j++) {
      float d = red[slot * 4 + 0][j][lane] + red[slot * 4 + 1][j][lane] +
                red[slot * 4 + 2][j][lane] + red[slot * 4 + 3][j][lane];
      const int m = mt * 16 + lq * 4 + j;
      float sv = SRCCOH ? cloadf(&srcF[(size_t)m * srcStride + srcOff + n])
                        : srcF[(size_t)m * srcStride + srcOff + n];
      float v = 2.0f * sigf(d + bn) * sv;
      cstoref(&dstF[(size_t)m * N + n], v);
      cstore_sh(dstS, (size_t)m * N + n, v, l15);
    }
  }
  __syncthreads();
}

// ---- cell2 K-quarter partials: WG pins W2[gates 0..3][nt][Kq-slice] (64x520 LDS).
// 4 m-chunks: stage A[32 x 512] coherent, 8 waves = 2 m-slots x 4 gates, K=512.
__device__ __forceinline__ void cell2_part(
    const unsigned short* X, const unsigned short* Hm,
    const unsigned short* pin, float* gp, int Kq, int nt, unsigned short* As) {
  const int tid = threadIdx.x, lane = tid & 63, wv = tid >> 6;
  const int mslot = wv & 1, gate = wv >> 1;
  const int l15 = lane & 15, lq = lane >> 4;
  const unsigned short* src = (Kq < 2) ? X : Hm;
  const int colOff = (Kq & 1) * 512;
  const unsigned short* wp = pin + (gate * 16 + l15) * 520 + lq * 8;
  for (int mc = 0; mc < 4; mc++) {
    stage_c<128>(As, 520, 0, src + (size_t)(mc * 32) * H_ + colOff, H_, 32);
    __syncthreads();
    const unsigned short* ap = As + (mslot * 16 + l15) * 520 + lq * 8;
    facc4 acc = {0.f, 0.f, 0.f, 0.f};
#pragma unroll
    for (int k = 0; k < 512; k += 32)
      acc = MFMA_BF16(*(const bfrag8*)(ap + k), *(const bfrag8*)(wp + k), acc, 0, 0, 0);
#pragma unroll
    for (int j = 0; j < 4; j++)
      cstoref(gp + ((size_t)Kq * B_ + mc * 32 + mslot * 16 + lq * 4 + j) * G_ +
                   gate * H_ + nt * 16 + l15, acc[j]);
    __syncthreads();
  }
}

// ---- cell1 K-quarter partials: concat [x(128)|h(1024)] = 1152 = 4 x 288.
__device__ __forceinline__ void cell1_part(
    const unsigned short* X, const unsigned short* Hm,
    const unsigned short* pin, float* gp, int Kq, int nt, unsigned short* As) {
  const int tid = threadIdx.x, lane = tid & 63, wv = tid >> 6;
  const int mslot = wv & 1, gate = wv >> 1;
  const int l15 = lane & 15, lq = lane >> 4;
  const int c0 = 288 * Kq;
  const unsigned short* wp = pin + (gate * 16 + l15) * 296 + lq * 8;
  for (int mc = 0; mc < 4; mc++) {
    if (c0 == 0) {  // x cols 0..127 + h cols 0..159
      stage_c<32>(As, 296, 0, X + (size_t)(mc * 32) * I_, I_, 32);
      stage_c<40>(As, 296, 128, Hm + (size_t)(mc * 32) * H_, H_, 32);
    } else {        // h cols c0-128 .. +288
      stage_c<72>(As, 296, 0, Hm + (size_t)(mc * 32) * H_ + (c0 - 128), H_, 32);
    }
    __syncthreads();
    const unsigned short* ap = As + (mslot * 16 + l15) * 296 + lq * 8;
    facc4 acc = {0.f, 0.f, 0.f, 0.f};
#pragma unroll
    for (int k = 0; k < 288; k += 32)
      acc = MFMA_BF16(*(const bfrag8*)(ap + k), *(const bfrag8*)(wp + k), acc, 0, 0, 0);
#pragma unroll
    for (int j = 0; j < 4; j++)
      cstoref(gp + ((size_t)Kq * B_ + mc * 32 + mslot * 16 + lq * 4 + j) * G_ +
                   gate * H_ + nt * 16 + l15, acc[j]);
    __syncthreads();
  }
}

__global__ __launch_bounds__(WGS, 1) void moglstm_kernel(
    const float* __restrict__ in_seq,
    const float* __restrict__ c1Q, const float* __restrict__ c1Qb,
    const float* __restrict__ c1R, const float* __restrict__ c1Rb,
    const float* __restrict__ c1Wih, const float* __restrict__ c1Whh,
    const float* __restrict__ c1bih, const float* __restrict__ c1bhh,
    const float* __restrict__ c2Q, const float* __restrict__ c2Qb,
    const float* __restrict__ c2R, const float* __restrict__ c2Rb,
    const float* __restrict__ c2Wih, const float* __restrict__ c2Whh,
    const float* __restrict__ c2bih, const float* __restrict__ c2bhh,
    const float* __restrict__ linW, const float* __restrict__ linb,
    char* ws, float* __restrict__ out) {
  __shared__ unsigned short pin_c2[64 * 520];   // 66,560 B
  __shared__ unsigned short pin_c1[64 * 296];   // 37,888 B
  __shared__ unsigned short As[16640];          // 33,280 B staging
  __shared__ float red[8][4][64];               //  8,192 B
  __shared__ float fin[WGS];                    //  2,048 B  -> 147,968 total

  GBar* bar = (GBar*)(ws + OFF_BAR);
  float* h1f0 = (float*)(ws + OFF_H1F);
  float* h1f1 = h1f0 + (size_t)B_ * H_;
  float* h2f0 = (float*)(ws + OFF_H2F);
  float* h2f1 = h2f0 + (size_t)B_ * H_;
  float* c1f = (float*)(ws + OFF_C1);
  float* c2f = (float*)(ws + OFF_C2);
  float* x1f = (float*)(ws + OFF_X1F);
  float* x2f = (float*)(ws + OFF_X2F);
  unsigned short* h1s0 = (unsigned short*)(ws + OFF_H1S);
  unsigned short* h1s1 = h1s0 + (size_t)B_ * H_;
  unsigned short* h2s0 = (unsigned short*)(ws + OFF_H2S);
  unsigned short* h2s1 = h2s0 + (size_t)B_ * H_;
  unsigned short* x1s = (unsigned short*)(ws + OFF_X1S);
  unsigned short* x2s = (unsigned short*)(ws + OFF_X2S);
  float* bs1 = (float*)(ws + OFF_BS1);
  float* bs2 = (float*)(ws + OFF_BS2);
  float* g1p = (float*)(ws + OFF_G1P);
  float* g2p = (float*)(ws + OFF_G2P);
  unsigned short* wq1bf = (unsigned short*)(ws + OFF_WQ1B);
  unsigned short* wr1bf = (unsigned short*)(ws + OFF_WR1B);
  unsigned short* wq2bf = (unsigned short*)(ws + OFF_WQ2B);
  unsigned short* wr2bf = (unsigned short*)(ws + OFF_WR2B);

  const int wg = blockIdx.x;
  const int tid = threadIdx.x;
  const int xcd = wg & 7;          // round-robin block->XCD heuristic
  const int idx = wg >> 3;         // 0..31
  const int Kq = idx >> 3;         // 0..3 (cell K-quarter)
  const int ntc = 8 * xcd + (idx & 7);   // cell nt (0..63), XCD-exclusive
  const int mtm = idx & 7;         // mog m-tile
  const int ntb2 = 8 * xcd + 2 * (idx >> 3);  // mog2 nt pair base, XCD-exclusive
  const bool doM1Q = ((xcd & 1) == 0) && (idx < 8);  // 32 WGs handle mog1-Q
  const int ntb1 = xcd;            // even xcd -> mog1-Q pair base (0,2,4,6)

  // ---- init: pin cell weight K-slices into LDS (fp32 -> bf16, plain loads)
  for (int i = tid; i < 64 * 512; i += WGS) {
    int r = i >> 9, k = i & 511;
    int row = (r >> 4) * H_ + ntc * 16 + (r & 15);
    float v = (Kq < 2) ? c2Wih[(size_t)row * H_ + Kq * 512 + k]
                       : c2Whh[(size_t)row * H_ + (Kq - 2) * 512 + k];
    pin_c2[r * 520 + k] = f2bf(v);
  }
  for (int i = tid; i < 64 * 288; i += WGS) {
    int r = i / 288, k = i - r * 288;
    int row = (r >> 4) * H_ + ntc * 16 + (r & 15);
    int kc = 288 * Kq + k;
    float v = (kc < 128) ? c1Wih[(size_t)row * I_ + kc]
                         : c1Whh[(size_t)row * H_ + (kc - 128)];
    pin_c1[r * 296 + k] = f2bf(v);
  }
  // ---- init: mog weights -> bf16 in ws (plain stores) + bias sums
  {
    size_t gt = (size_t)wg * WGS + tid;
    const size_t gs = (size_t)NWG * WGS;
    for (size_t i = gt; i < 3ull * I_ * H_; i += gs) wq1bf[i] = f2bf(c1Q[i]);
    for (size_t i = gt; i < 2ull * H_ * I_; i += gs) wr1bf[i] = f2bf(c1R[i]);
    for (size_t i = gt; i < 3ull * H_ * H_; i += gs) wq2bf[i] = f2bf(c2Q[i]);
    for (size_t i = gt; i < 2ull * H_ * H_; i += gs) wr2bf[i] = f2bf(c2R[i]);
    for (size_t i = gt; i < (size_t)G_; i += gs) bs1[i] = c1bih[i] + c1bhh[i];
    for (size_t i = gt; i < (size_t)G_; i += gs) bs2[i] = c2bih[i] + c2bhh[i];
  }
  gbar_init(bar);  // full fences ONCE: publish plain-stored weights

  // phase p: layer-1 step t=p and layer-2 step t=p-1
  for (int p = 0; p <= T_; ++p) {
    const int q = p & 1;
    const bool doL1 = (p < T_);
    const bool doL2 = (p > 0);
    float* h1q = q ? h1f1 : h1f0;
    float* h1o = q ? h1f0 : h1f1;
    unsigned short* h1sq = q ? h1s1 : h1s0;
    unsigned short* h1so = q ? h1s0 : h1s1;
    float* h2q2 = q ? h2f0 : h2f1;
    float* h2o = q ? h2f1 : h2f0;
    unsigned short* h2sq2 = q ? h2s0 : h2s1;
    unsigned short* h2so = q ? h2s1 : h2s0;

    // s0: Q1
    if (doL2)
      mog_unit<1024, true>(h2sq2, wq2bf, c2Qb, h1q, H_, 0, x2f, x2s, H_, mtm, ntb2, As, red);
    if (doL1 && doM1Q)
      mog_unit<1024, false>(h1sq, wq1bf, c1Qb, in_seq, T_ * I_, p * I_, x1f, x1s, I_, idx, ntb1, As, red);
    gbar(bar);
    // s1: R1 (both layers, all WGs)
    if (doL2)
      mog_unit<1024, true>(x2s, wr2bf, c2Rb, h2q2, H_, 0, h2q2, h2sq2, H_, mtm, ntb2, As, red);
    if (doL1)
      mog_unit<128, true>(x1s, wr1bf, c1Rb, h1q, H_, 0, h1q, h1sq, H_, mtm, ntb2, As, red);
    gbar(bar);
    // s2: Q2
    if (doL2)
      mog_unit<1024, true>(h2sq2, wq2bf + 1ull * H_ * H_, c2Qb + H_, x2f, H_, 0, x2f, x2s, H_, mtm, ntb2, As, red);
    if (doL1 && doM1Q)
      mog_unit<1024, true>(h1sq, wq1bf + 1ull * I_ * H_, c1Qb + I_, x1f, I_, 0, x1f, x1s, I_, idx, ntb1, As, red);
    gbar(bar);
    // s3: R2
    if (doL2)
      mog_unit<1024, true>(x2s, wr2bf + 1ull * H_ * H_, c2Rb + H_, h2q2, H_, 0, h2q2, h2sq2, H_, mtm, ntb2, As, red);
    if (doL1)
      mog_unit<128, true>(x1s, wr1bf + 1ull * H_ * I_, c1Rb + H_, h1q, H_, 0, h1q, h1sq, H_, mtm, ntb2, As, red);
    gbar(bar);
    // s4: Q3
    if (doL2)
      mog_unit<1024, true>(h2sq2, wq2bf + 2ull * H_ * H_, c2Qb + 2 * H_, x2f, H_, 0, x2f, x2s, H_, mtm, ntb2, As, red);
    if (doL1 && doM1Q)
      mog_unit<1024, true>(h1sq, wq1bf + 2ull * I_ * H_, c1Qb + 2 * I_, x1f, I_, 0, x1f, x1s, I_, idx, ntb1, As, red);
    gbar(bar);
    // s5: cell K-quarter partials (pinned LDS weights), fp32 coherent planes
    if (doL2) cell2_part(x2s, h2sq2, pin_c2, g2p, Kq, ntc, As);
    if (doL1) cell1_part(x1s, h1sq, pin_c1, g1p, Kq, ntc, As);
    gbar(bar);
    // s6: reduce 4 Kq + LSTM epilogue; 1 (cell, m, n-pair) per thread
    {
      const int e = wg * WGS + tid;
      const int cell = e >> 16;
      const int pr = e & 65535;
      const int m = pr >> 9;
      const int n2 = (pr & 511) * 2;
      if (cell ? doL2 : doL1) {
        const float* gp = cell ? g2p : g1p;
        const float* bs = cell ? bs2 : bs1;
        float* cst = cell ? c2f : c1f;
        float* hF = cell ? h2o : h1o;
        unsigned short* hS = cell ? h2so : h1so;
        unsigned pk = 0;
#pragma unroll
        for (int d = 0; d < 2; d++) {
          const int nn = n2 + d;
          float g4[4];
#pragma unroll
          for (int gg = 0; gg < 4; gg++) {
            float s = 0.f;
#pragma unroll
            for (int r = 0; r < 4; r++)
              s += cloadf(gp + ((size_t)r * B_ + m) * G_ + gg * H_ + nn);
            g4[gg] = s + bs[gg * H_ + nn];
          }
          const size_t idx2 = (size_t)m * H_ + nn;
          float cn = sigf(g4[1]) * cloadf(&cst[idx2]) + sigf(g4[0]) * tanhf(g4[2]);
          float hn = sigf(g4[3]) * tanhf(cn);
          cstoref(&cst[idx2], cn);
          cstoref(&hF[idx2], hn);
          pk |= ((unsigned)f2bf(hn)) << (16 * d);
        }
        cstoreu((unsigned*)(hS + (size_t)m * H_ + n2), pk);
      }
    }
    gbar(bar);
  }

  // ---- final linear: out[b] = dot(h2f0[b,:], linW) + linb
  if (wg == 0) {
    const int b = tid >> 2, qq = tid & 3;
    const float* row = h2f0 + (size_t)b * H_ + qq * 256;
    const float* w = linW + qq * 256;
    float s = 0.f;
    for (int k = 0; k < 256; k++) s += cloadf(&row[k]) * w[k];
    fin[tid] = s;
    __syncthreads();
    if (tid < B_)
      out[tid] = fin[tid * 4] + fin[tid * 4 + 1] + fin[tid * 4 + 2] + fin[tid * 4 + 3] + linb[0];
  }
}

extern "C" void kernel_launch(void* const* d_in, const int* in_sizes, int n_in,
                              void* d_out, int out_size, void* d_ws, size_t ws_size,
                              hipStream_t stream) {
  const float* in_seq = (const float*)d_in[0];
  const float* c1Q = (const float*)d_in[1];
  const float* c1Qb = (const float*)d_in[2];
  const float* c1R = (const float*)d_in[3];
  const float* c1Rb = (const float*)d_in[4];
  const float* c1Wih = (const float*)d_in[5];
  const float* c1Whh = (const float*)d_in[6];
  const float* c1bih = (const float*)d_in[7];
  const float* c1bhh = (const float*)d_in[8];
  const float* c2Q = (const float*)d_in[9];
  const float* c2Qb = (const float*)d_in[10];
  const float* c2R = (const float*)d_in[11];
  const float* c2Rb = (const float*)d_in[12];
  const float* c2Wih = (const float*)d_in[13];
  const float* c2Whh = (const float*)d_in[14];
  const float* c2bih = (const float*)d_in[15];
  const float* c2bhh = (const float*)d_in[16];
  const float* linW = (const float*)d_in[17];
  const float* linb = (const float*)d_in[18];

  hipMemsetAsync(d_ws, 0, ZERO_BYTES, stream);
  moglstm_kernel<<<dim3(NWG), dim3(WGS), 0, stream>>>(
      in_seq, c1Q, c1Qb, c1R, c1Rb, c1Wih, c1Whh, c1bih, c1bhh,
      c2Q, c2Qb, c2R, c2Rb, c2Wih, c2Whh, c2bih, c2bhh,
      linW, linb, (char*)d_ws, (float*)d_out);
}